// Round 6
// baseline (669.273 us; speedup 1.0000x reference)
//
#include <hip/hip_runtime.h>

typedef __bf16 bf16;
typedef __bf16 bf16x8 __attribute__((ext_vector_type(8)));
typedef __bf16 bf16x4 __attribute__((ext_vector_type(4)));
typedef __bf16 bf16x2 __attribute__((ext_vector_type(2)));
typedef float  f32x4  __attribute__((ext_vector_type(4)));

static_assert(sizeof(bf16x8) == 16, "bf16x8 must be 16B");

#define MFMA16(a, b, c) __builtin_amdgcn_mfma_f32_16x16x32_bf16((a), (b), (c), 0, 0, 0)

__device__ __forceinline__ void gload_lds16(const void* g, void* l) {
    __builtin_amdgcn_global_load_lds(
        (const __attribute__((address_space(1))) void*)(uintptr_t)g,
        (__attribute__((address_space(3))) void*)(uintptr_t)l,
        16, 0, 0);
}

// ---------------------------------------------------------------------------
// f32 -> bf16 cast, 8 elements/thread.
// ---------------------------------------------------------------------------
__global__ __launch_bounds__(256)
void cast_f32_bf16(const float* __restrict__ in, bf16* __restrict__ out, int n8)
{
    const int i = blockIdx.x * 256 + threadIdx.x;
    if (i >= n8) return;
    const float4 a = ((const float4*)in)[i * 2];
    const float4 b = ((const float4*)in)[i * 2 + 1];
    bf16x8 o;
    o[0] = (bf16)a.x; o[1] = (bf16)a.y; o[2] = (bf16)a.z; o[3] = (bf16)a.w;
    o[4] = (bf16)b.x; o[5] = (bf16)b.y; o[6] = (bf16)b.z; o[7] = (bf16)b.w;
    ((bf16x8*)out)[i] = o;
}

// ---------------------------------------------------------------------------
// GEMM: C[M,N] = A[M,K] * W[N,K]^T, bf16 in, f32 accumulate, OT out.
// tile 128x128, BK=32, block 256 (4 waves 2x2, each 64x64). m97 structure.
// XCD-bijective block swizzle (nwg % 8 == 0 for all launches): each XCD's
// resident blocks cover a contiguous C-region -> A-panels (512 KB) are
// fetched once per XCD L2 instead of 8x across XCDs.
// ---------------------------------------------------------------------------
template <typename OT>
__global__ __launch_bounds__(256)
void gemm_bt(const bf16* __restrict__ A, const bf16* __restrict__ W,
             int K, int ldc, OT* __restrict__ C)
{
    __shared__ bf16 As[128 * 32];
    __shared__ bf16 Bs[128 * 32];

    const int nwg = gridDim.x * gridDim.y;
    const int lin = blockIdx.y * gridDim.x + blockIdx.x;
    const int cpx = nwg >> 3;                 // nwg % 8 == 0
    const int swz = (lin & 7) * cpx + (lin >> 3);
    const int n0 = (swz % gridDim.x) * 128;
    const int m0 = (swz / gridDim.x) * 128;

    const int tid  = threadIdx.x;
    const int lane = tid & 63;
    const int wid  = tid >> 6;
    const int wm   = wid >> 1;
    const int wn   = wid & 1;
    const int quad = lane >> 4;
    const int l16  = lane & 15;

    const int srow = wid * 32 + (lane >> 2);
    const int scol = (lane & 3) * 8;
    const bf16* ag = A + (size_t)(m0 + srow) * K + scol;
    const bf16* wg = W + (size_t)(n0 + srow) * K + scol;
    bf16* al = As + wid * 1024;
    bf16* bl = Bs + wid * 1024;

    const bf16* afr = As + (wm * 64 + l16) * 32 + quad * 8;
    const bf16* bfr = Bs + (wn * 64 + l16) * 32 + quad * 8;

    f32x4 acc[4][4];
#pragma unroll
    for (int i = 0; i < 4; i++)
#pragma unroll
        for (int j = 0; j < 4; j++) acc[i][j] = f32x4{0.f, 0.f, 0.f, 0.f};

    for (int kt = 0; kt < K; kt += 32) {
        __syncthreads();
        gload_lds16(ag,          al);
        gload_lds16(ag + 16 * K, al + 512);
        gload_lds16(wg,          bl);
        gload_lds16(wg + 16 * K, bl + 512);
        ag += 32; wg += 32;
        __syncthreads();

        bf16x8 af[4], bfv[4];
#pragma unroll
        for (int i = 0; i < 4; i++) af[i]  = *(const bf16x8*)(afr + i * 16 * 32);
#pragma unroll
        for (int i = 0; i < 4; i++) bfv[i] = *(const bf16x8*)(bfr + i * 16 * 32);
#pragma unroll
        for (int mi = 0; mi < 4; mi++)
#pragma unroll
            for (int ni = 0; ni < 4; ni++)
                acc[mi][ni] = MFMA16(af[mi], bfv[ni], acc[mi][ni]);
    }

#pragma unroll
    for (int mi = 0; mi < 4; mi++) {
        const int row = m0 + wm * 64 + mi * 16 + quad * 4;
#pragma unroll
        for (int ni = 0; ni < 4; ni++) {
            const int col = n0 + wn * 64 + ni * 16 + l16;
#pragma unroll
            for (int r = 0; r < 4; r++)
                C[(size_t)(row + r) * ldc + col] = (OT)acc[mi][ni][r];
        }
    }
}

// ---------------------------------------------------------------------------
// Fused per-head RMSNorm (over 128) + RoPE, in place on q (16 heads) and
// k (4 heads) inside qkv [8192, 3072] (bf16). fc/norm weights are f32.
// Q heads additionally scaled by (1/sqrt(128))*log2(e) for exp2-domain softmax.
// ---------------------------------------------------------------------------
__global__ __launch_bounds__(256)
void normrope(bf16* __restrict__ qkv, const float* __restrict__ fc,
              const float* __restrict__ qw, const float* __restrict__ kw)
{
    const int row  = blockIdx.x * 4 + (threadIdx.x >> 6);
    const int lane = threadIdx.x & 63;
    const int slot = row % 20;
    const int tok  = row / 20;       // b*4096 + s
    const int s    = tok & 4095;

    const float* w; int off; float post;
    if (slot < 16) { off = slot * 128;               w = qw; post = 0.12751681555f; }
    else           { off = 2048 + (slot - 16) * 128; w = kw; post = 1.0f; }

    bf16* p = qkv + (size_t)tok * 3072 + off;

    bf16x2 v = *(const bf16x2*)(p + 2 * lane);
    float x0 = (float)v[0], x1 = (float)v[1];

    float ss = x0 * x0 + x1 * x1;
    ss += __shfl_xor(ss, 1);  ss += __shfl_xor(ss, 2);  ss += __shfl_xor(ss, 4);
    ss += __shfl_xor(ss, 8);  ss += __shfl_xor(ss, 16); ss += __shfl_xor(ss, 32);
    const float r = rsqrtf(ss * (1.0f / 128.0f) + 1e-6f) * post;

    const float xn0 = x0 * r * w[2 * lane], xn1 = x1 * r * w[2 * lane + 1];

    const float2 cs = ((const float2*)fc)[(size_t)s * 64 + lane];
    const float c = cs.x, sn = cs.y;

    bf16x2 o;
    o[0] = (bf16)(xn0 * c - xn1 * sn);
    o[1] = (bf16)(xn0 * sn + xn1 * c);
    *(bf16x2*)(p + 2 * lane) = o;
}

// ---------------------------------------------------------------------------
// V transpose: v[b,s,kvh,d] (strided in qkv) -> vT[b,kvh,d,s]
// LDS tile transpose: 64 s x 128 d per block; coalesced reads (256B rows)
// and coalesced writes (128B half-rows x2).
// ---------------------------------------------------------------------------
__global__ __launch_bounds__(256)
void transpose_v(const bf16* __restrict__ qkv, bf16* __restrict__ vT)
{
    __shared__ bf16 T[64][130];
    const int st = blockIdx.x;        // s-tile (64 rows)
    const int bk = blockIdx.y;        // b*4 + kvh
    const int b = bk >> 2, kvh = bk & 3;
    const int w = threadIdx.x >> 6, lane = threadIdx.x & 63;
    const int s0 = st * 64;

    const bf16* src = qkv + (size_t)(b * 4096 + s0) * 3072 + 2560 + kvh * 128;
#pragma unroll
    for (int i = 0; i < 16; i++) {
        const int s = w * 16 + i;
        const bf16x2 v = *(const bf16x2*)(src + (size_t)s * 3072 + 2 * lane);
        *(bf16x2*)(&T[s][2 * lane]) = v;
    }
    __syncthreads();

    bf16* dst = vT + ((size_t)bk * 128) * 4096 + s0;
#pragma unroll
    for (int i = 0; i < 16; i++) {
        const int d = w * 32 + 2 * i + (lane >> 5);
        const int s = (lane & 31) * 2;
        bf16x2 o;
        o[0] = T[s][d];
        o[1] = T[s + 1][d];
        *(bf16x2*)(dst + (size_t)d * 4096 + s) = o;
    }
}

// ---------------------------------------------------------------------------
// Causal flash attention, GQA 4:1. Q-tile 128 (4 waves x 32 rows), KV-tile 64.
// Block processes q-tile pair (bx, 31-bx): uniform 66 units/block, 512 blocks.
//
// K AND V both double-buffered in LDS (async global_load_lds, XOR-8 granule
// swizzle), ONE barrier per tile. Staging for tile t+1 (V) and t+2 (K) is
// issued IMMEDIATELY after the (E) barrier of tile t, so each prefetch has a
// full tile of compute (QK + PV + softmax) to land before the (E) that
// drains it. WAR safety: the buffer overwritten (Vs[(t+1)&1] / Ks[t&1]) was
// last read by PV[t-1] / QK[t], both strictly before (E) of tile t.
// LDS 80 KB -> 2 blocks/CU (grid is exactly 2/CU).
//
// T15 QK-lookahead retained: softmax at tile t consumes scores produced at
// the end of tile t-1; QK[t+1] is issued right after staging, before PV[t].
// Schedule per step:
//   softmax(SA[t]) -> Ps        [VALU; input one tile old]
//   (E) barrier                  [V[t], K[t+1] landed]
//   issue V[t+1] -> Vs[(t+1)&1], K[t+2] -> Ks[t&1]
//   QK[t+1] -> SB                [MFMA]
//   PV[t] from Vs[t&1]           [MFMA]
// ntiles always even -> 2x-unrolled loop with named SA/SB. Defer-max
// (THR=8, exp2 domain); setprio(1) around MFMA clusters.
// ---------------------------------------------------------------------------
__global__ __launch_bounds__(256, 2)
void flash(const bf16* __restrict__ qkv, const bf16* __restrict__ vT,
           bf16* __restrict__ out)
{
    const int bh  = blockIdx.y;
    const int b   = bh >> 4, h = bh & 15;
    const int kvh = h >> 2;

    const int tid  = threadIdx.x;
    const int lane = tid & 63;
    const int wid  = tid >> 6;
    const int quad = lane >> 4;
    const int l16  = lane & 15;
    const int key  = l16 & 7;        // read-side swizzle key (row&7 == l16&7 everywhere)

    __shared__ bf16 Ks[2][64 * 128]; // [kv][d], 16 granules/row, swizzled
    __shared__ bf16 Vs[2][128 * 64]; // [d][kv], 8 granules/row, swizzled
    __shared__ bf16 Ps[128 * 64];    // [q][kv], 8 granules/row, swizzled, wave-private rows

    const bf16* kbase = qkv + (size_t)b * 4096 * 3072 + 2048 + kvh * 128;
    const bf16* vbase = vT + ((size_t)(b * 4 + kvh) * 128) * 4096;

    // staging lane decomposition
    const int krow_off = lane >> 4;            // 0..3   (4 rows / 1KB instr)
    const int kcolg    = lane & 15;            // 16B granule within 256B K row
    const int vrow_off = lane >> 3;            // 0..7   (8 rows / 1KB instr)
    const int vcolg    = lane & 7;             // granule within 128B V row

    for (int pass = 0; pass < 2; ++pass) {
        const int qt = pass ? (31 - blockIdx.x) : blockIdx.x;
        const int q0 = qt * 128;
        const int ntiles = qt * 2 + 2;          // always even

        __syncthreads();   // buffers free from previous pass, staging drained
        // preload K[0] -> Ks[0]
#pragma unroll
        for (int i = 0; i < 4; i++) {
            const int r0 = wid * 16 + i * 4;
            const int rk = r0 + krow_off;
            const int gc = (kcolg ^ (rk & 7)) * 8;
            gload_lds16(kbase + (size_t)rk * 3072 + gc, &Ks[0][r0 * 128]);
        }

        // Q fragments, 2 m-tiles x 4 k-steps (overlaps preload)
        bf16x8 qf[2][4];
        const bf16* qbase = qkv + ((size_t)(b * 4096 + q0 + wid * 32)) * 3072 + h * 128;
#pragma unroll
        for (int mt = 0; mt < 2; mt++)
#pragma unroll
            for (int ks = 0; ks < 4; ks++)
                qf[mt][ks] = *(const bf16x8*)(qbase + (size_t)(mt * 16 + l16) * 3072 + ks * 32 + quad * 8);

        f32x4 oacc[2][8];
#pragma unroll
        for (int mt = 0; mt < 2; mt++)
#pragma unroll
            for (int nd = 0; nd < 8; nd++) oacc[mt][nd] = f32x4{0.f, 0.f, 0.f, 0.f};
        float mrow[2], lrow[2];
#pragma unroll
        for (int mt = 0; mt < 2; mt++) { mrow[mt] = -__builtin_inff(); lrow[mt] = 0.f; }

        __syncthreads();   // K[0] landed

        // issue V[0] -> Vs[0] and K[1] -> Ks[1] (ntiles >= 2 always)
#pragma unroll
        for (int i = 0; i < 4; i++) {
            const int r0 = wid * 32 + i * 8;
            const int dv = r0 + vrow_off;
            const int gc = (vcolg ^ (dv & 7)) * 8;
            gload_lds16(vbase + (size_t)dv * 4096 + gc, &Vs[0][r0 * 64]);
        }
#pragma unroll
        for (int i = 0; i < 4; i++) {
            const int r0 = wid * 16 + i * 4;
            const int rk = r0 + krow_off;
            const int gc = (kcolg ^ (rk & 7)) * 8;
            gload_lds16(kbase + (size_t)(64 + rk) * 3072 + gc, &Ks[1][r0 * 128]);
        }

        f32x4 sA[2][4], sB[2][4];

        // prologue QK[0] -> sA (from Ks[0])
        {
#pragma unroll
            for (int mt = 0; mt < 2; mt++)
#pragma unroll
                for (int nt = 0; nt < 4; nt++) sA[mt][nt] = f32x4{0.f, 0.f, 0.f, 0.f};
            __builtin_amdgcn_s_setprio(1);
#pragma unroll
            for (int ks = 0; ks < 4; ks++) {
                bf16x8 kf[4];
#pragma unroll
                for (int nt = 0; nt < 4; nt++)
                    kf[nt] = *(const bf16x8*)(&Ks[0][(nt * 16 + l16) * 128 + (((ks * 4 + quad) ^ key) * 8)]);
#pragma unroll
                for (int mt = 0; mt < 2; mt++)
#pragma unroll
                    for (int nt = 0; nt < 4; nt++)
                        sA[mt][nt] = MFMA16(kf[nt], qf[mt][ks], sA[mt][nt]);
            }
            __builtin_amdgcn_s_setprio(0);
        }

        // one pipeline step: softmax(SA of tile t); (E); issue V[t+1],K[t+2];
        // QK[t+1]->SB; PV[t]
        auto step = [&](int t, f32x4 (&SA)[2][4], f32x4 (&SB)[2][4]) {
            const int kv0 = t * 64;

            if (kv0 + 63 > q0) {   // diagonal tiles: causal mask (kv > q)
#pragma unroll
                for (int mt = 0; mt < 2; mt++) {
                    const int qg = q0 + wid * 32 + mt * 16 + l16;
#pragma unroll
                    for (int nt = 0; nt < 4; nt++)
#pragma unroll
                        for (int r = 0; r < 4; r++) {
                            const int kvg = kv0 + nt * 16 + quad * 4 + r;
                            if (kvg > qg) SA[mt][nt][r] = -1e30f;
                        }
                }
            }

            // ---- online softmax: lane-local row (q = l16) ----
            float pm[2];
#pragma unroll
            for (int mt = 0; mt < 2; mt++) {
                float t8[8];
#pragma unroll
                for (int nt = 0; nt < 4; nt++) {
                    t8[2 * nt]     = fmaxf(SA[mt][nt][0], SA[mt][nt][1]);
                    t8[2 * nt + 1] = fmaxf(SA[mt][nt][2], SA[mt][nt][3]);
                }
                float m = fmaxf(fmaxf(fmaxf(t8[0], t8[1]), fmaxf(t8[2], t8[3])),
                                fmaxf(fmaxf(t8[4], t8[5]), fmaxf(t8[6], t8[7])));
                m = fmaxf(m, __shfl_xor(m, 16));
                m = fmaxf(m, __shfl_xor(m, 32));
                pm[mt] = m;
            }

            // defer-max: skip rescale while the running max holds within THR=8
            const bool rescale =
                !__all((pm[0] - mrow[0] <= 8.f) && (pm[1] - mrow[1] <= 8.f));
            if (rescale) {
#pragma unroll
                for (int mt = 0; mt < 2; mt++) {
                    const float mnew  = fmaxf(mrow[mt], pm[mt]);
                    const float alpha = exp2f(mrow[mt] - mnew);
                    mrow[mt] = mnew;
                    lrow[mt] *= alpha;
                    float ar[4];   // transpose alpha (q=l16) -> PV rows (q=quad*4+r)
#pragma unroll
                    for (int r = 0; r < 4; r++) ar[r] = __shfl(alpha, quad * 4 + r);
#pragma unroll
                    for (int nd = 0; nd < 8; nd++)
#pragma unroll
                        for (int r = 0; r < 4; r++) oacc[mt][nd][r] *= ar[r];
                }
            }

            // exps + packed P stores (4 consecutive kv -> b64, swizzled) + sums
#pragma unroll
            for (int mt = 0; mt < 2; mt++) {
                const int prow = wid * 32 + mt * 16 + l16;
                float sn[4];
#pragma unroll
                for (int nt = 0; nt < 4; nt++) {
                    const float p0 = exp2f(SA[mt][nt][0] - mrow[mt]);
                    const float p1 = exp2f(SA[mt][nt][1] - mrow[mt]);
                    const float p2 = exp2f(SA[mt][nt][2] - mrow[mt]);
                    const float p3 = exp2f(SA[mt][nt][3] - mrow[mt]);
                    sn[nt] = (p0 + p1) + (p2 + p3);
                    bf16x4 h4;
                    h4[0] = (bf16)p0; h4[1] = (bf16)p1;
                    h4[2] = (bf16)p2; h4[3] = (bf16)p3;
                    const int g = (2 * nt + (quad >> 1)) ^ key;
                    *(bf16x4*)(&Ps[prow * 64 + g * 8 + (quad & 1) * 4]) = h4;
                }
                float s = (sn[0] + sn[1]) + (sn[2] + sn[3]);
                s += __shfl_xor(s, 16);
                s += __shfl_xor(s, 32);
                lrow[mt] += s;
            }

            __syncthreads();   // (E) V[t], K[t+1] landed; old-buffer readers done

            // staging first: V[t+1] -> Vs[(t+1)&1], K[t+2] -> Ks[t&1]
            // (full tile of cover until next step's (E))
            if (t + 1 < ntiles) {
                const int kvv = (t + 1) * 64;
                bf16* vdst = &Vs[(t + 1) & 1][0];
#pragma unroll
                for (int i = 0; i < 4; i++) {
                    const int r0 = wid * 32 + i * 8;
                    const int dv = r0 + vrow_off;
                    const int gc = (vcolg ^ (dv & 7)) * 8;
                    gload_lds16(vbase + (size_t)dv * 4096 + kvv + gc, vdst + r0 * 64);
                }
                if (t + 2 < ntiles) {
                    const int kvn = (t + 2) * 64;
                    bf16* kdst = &Ks[t & 1][0];
#pragma unroll
                    for (int i = 0; i < 4; i++) {
                        const int r0 = wid * 16 + i * 4;
                        const int rk = r0 + krow_off;
                        const int gc = (kcolg ^ (rk & 7)) * 8;
                        gload_lds16(kbase + (size_t)(kvn + rk) * 3072 + gc, kdst + r0 * 128);
                    }
                }
            }

            // QK[t+1] (results needed soonest; covers Ps->PV lgkm)
            if (t + 1 < ntiles) {
#pragma unroll
                for (int mt = 0; mt < 2; mt++)
#pragma unroll
                    for (int nt = 0; nt < 4; nt++) SB[mt][nt] = f32x4{0.f, 0.f, 0.f, 0.f};
                __builtin_amdgcn_s_setprio(1);
#pragma unroll
                for (int ks = 0; ks < 4; ks++) {
                    bf16x8 kf[4];
#pragma unroll
                    for (int nt = 0; nt < 4; nt++)
                        kf[nt] = *(const bf16x8*)(&Ks[(t + 1) & 1][(nt * 16 + l16) * 128 + (((ks * 4 + quad) ^ key) * 8)]);
#pragma unroll
                    for (int mt = 0; mt < 2; mt++)
#pragma unroll
                        for (int nt = 0; nt < 4; nt++)
                            SB[mt][nt] = MFMA16(kf[nt], qf[mt][ks], SB[mt][nt]);
                }
                __builtin_amdgcn_s_setprio(0);
            }

            // O += P V from Vs[t&1]
            __builtin_amdgcn_s_setprio(1);
#pragma unroll
            for (int ks = 0; ks < 2; ks++) {
                bf16x8 pf[2];
#pragma unroll
                for (int mt = 0; mt < 2; mt++)
                    pf[mt] = *(const bf16x8*)(&Ps[(wid * 32 + mt * 16 + l16) * 64 + (((ks * 4 + quad) ^ key) * 8)]);
#pragma unroll
                for (int nd = 0; nd < 8; nd++) {
                    const bf16x8 vf = *(const bf16x8*)(&Vs[t & 1][(nd * 16 + l16) * 64 + (((ks * 4 + quad) ^ key) * 8)]);
#pragma unroll
                    for (int mt = 0; mt < 2; mt++)
                        oacc[mt][nd] = MFMA16(pf[mt], vf, oacc[mt][nd]);
                }
            }
            __builtin_amdgcn_s_setprio(0);
        };

        for (int t = 0; t < ntiles; t += 2) {
            step(t,     sA, sB);
            step(t + 1, sB, sA);
        }

        // epilogue: O / l -> out[b, s, h*128 + d]; 1/l transposed to PV rows
#pragma unroll
        for (int mt = 0; mt < 2; mt++) {
            const float inv = 1.0f / lrow[mt];
            float invr[4];
#pragma unroll
            for (int r = 0; r < 4; r++) invr[r] = __shfl(inv, quad * 4 + r);
#pragma unroll
            for (int r = 0; r < 4; r++) {
                const size_t srow = (size_t)(b * 4096 + q0 + wid * 32 + mt * 16 + quad * 4 + r);
#pragma unroll
                for (int nd = 0; nd < 8; nd++)
                    out[srow * 2048 + h * 128 + nd * 16 + l16] = (bf16)(oacc[mt][nd][r] * invr[r]);
            }
        }
    }
}

// ---------------------------------------------------------------------------
extern "C" void kernel_launch(void* const* d_in, const int* in_sizes, int n_in,
                              void* d_out, int out_size, void* d_ws, size_t ws_size,
                              hipStream_t stream)
{
    const float* x   = (const float*)d_in[0];
    const float* fc  = (const float*)d_in[1];
    const float* wq  = (const float*)d_in[2];
    const float* wk  = (const float*)d_in[3];
    const float* wv  = (const float*)d_in[4];
    const float* wo  = (const float*)d_in[5];
    const float* qnw = (const float*)d_in[6];
    const float* knw = (const float*)d_in[7];
    float* out = (float*)d_out;

    // workspace layout (100 MB total, with aliasing):
    //   [0,        50331648)  qkv bf16 [8192,3072]
    //   [50331648, 58720256)  vT  bf16 [2,4,128,4096]
    //   [58720256, 92274688)  xb (x as bf16) during gemm1, then att (flash out)
    //   [92274688, 104857600) wqkv bf16 [3072,2048] during gemm1, then wo bf16
    char* ws = (char*)d_ws;
    bf16* qkv = (bf16*)ws;
    bf16* vT  = (bf16*)(ws + 50331648);
    bf16* xb  = (bf16*)(ws + 58720256);
    bf16* att = xb;
    bf16* wb  = (bf16*)(ws + 92274688);
    bf16* wob = wb;

    // 0) casts: x -> bf16, [wq;wk;wv] -> bf16 (contiguous rows)
    cast_f32_bf16<<<dim3(8192), 256, 0, stream>>>(x, xb, 2097152);
    cast_f32_bf16<<<dim3(2048), 256, 0, stream>>>(wq, wb, 524288);
    cast_f32_bf16<<<dim3(512),  256, 0, stream>>>(wk, wb + 2048 * 2048, 131072);
    cast_f32_bf16<<<dim3(512),  256, 0, stream>>>(wv, wb + 2560 * 2048, 131072);
    // 1) fused QKV projection: qkv[8192,3072] = xb @ wb^T (XCD-swizzled)
    gemm_bt<bf16><<<dim3(24, 64), 256, 0, stream>>>(xb, wb, 2048, 3072, qkv);
    // 2) RMSNorm + RoPE on q,k heads in place (q pre-scaled for exp2 softmax)
    normrope<<<dim3(40960), 256, 0, stream>>>(qkv, fc, qnw, knw);
    // 3) V -> V^T (LDS tile transpose, coalesced both sides)
    transpose_v<<<dim3(64, 8), 256, 0, stream>>>(qkv, vT);
    // 4) causal flash attention: K+V double-buffered, 1 barrier/tile,
    //    staging issued right after the barrier (full-tile cover)
    flash<<<dim3(16, 32), 256, 0, stream>>>(qkv, vT, att);
    // 5) wo -> bf16 (aliases wqkv region - dead after gemm1)
    cast_f32_bf16<<<dim3(2048), 256, 0, stream>>>(wo, wob, 524288);
    // 6) output projection: out = att @ wob^T (f32 out, XCD-swizzled)
    gemm_bt<float><<<dim3(16, 64), 256, 0, stream>>>(att, wob, 2048, 2048, out);
}

// Round 7
// 632.868 us; speedup vs baseline: 1.0575x; 1.0575x over previous
//
#include <hip/hip_runtime.h>

typedef __bf16 bf16;
typedef __bf16 bf16x8 __attribute__((ext_vector_type(8)));
typedef __bf16 bf16x4 __attribute__((ext_vector_type(4)));
typedef __bf16 bf16x2 __attribute__((ext_vector_type(2)));
typedef float  f32x4  __attribute__((ext_vector_type(4)));

static_assert(sizeof(bf16x8) == 16, "bf16x8 must be 16B");

#define MFMA16(a, b, c) __builtin_amdgcn_mfma_f32_16x16x32_bf16((a), (b), (c), 0, 0, 0)

__device__ __forceinline__ void gload_lds16(const void* g, void* l) {
    __builtin_amdgcn_global_load_lds(
        (const __attribute__((address_space(1))) void*)(uintptr_t)g,
        (__attribute__((address_space(3))) void*)(uintptr_t)l,
        16, 0, 0);
}

// ---------------------------------------------------------------------------
// f32 -> bf16 cast, 8 elements/thread.
// ---------------------------------------------------------------------------
__global__ __launch_bounds__(256)
void cast_f32_bf16(const float* __restrict__ in, bf16* __restrict__ out, int n8)
{
    const int i = blockIdx.x * 256 + threadIdx.x;
    if (i >= n8) return;
    const float4 a = ((const float4*)in)[i * 2];
    const float4 b = ((const float4*)in)[i * 2 + 1];
    bf16x8 o;
    o[0] = (bf16)a.x; o[1] = (bf16)a.y; o[2] = (bf16)a.z; o[3] = (bf16)a.w;
    o[4] = (bf16)b.x; o[5] = (bf16)b.y; o[6] = (bf16)b.z; o[7] = (bf16)b.w;
    ((bf16x8*)out)[i] = o;
}

// ---------------------------------------------------------------------------
// GEMM: C[M,N] = A[M,K] * W[N,K]^T, bf16 in, f32 accumulate, OT out.
// tile 128x128, BK=64, block 256 (4 waves 2x2, each 64x64).
// LDS tiles are XOR-granule swizzled (LDS[row][g] holds global granule
// g^(row&7)): staging stays lane-linear global_load_lds (pre-swizzled
// per-lane global source), fragment ds_read_b128 is <=2-way conflicted.
// Half the barriers of the BK=32 m97 loop (32 iters for K=2048).
// ---------------------------------------------------------------------------
template <typename OT>
__global__ __launch_bounds__(256)
void gemm_bt(const bf16* __restrict__ A, const bf16* __restrict__ W,
             int K, int ldc, OT* __restrict__ C)
{
    __shared__ bf16 As[128 * 64];
    __shared__ bf16 Bs[128 * 64];

    const int n0 = blockIdx.x * 128;
    const int m0 = blockIdx.y * 128;

    const int tid  = threadIdx.x;
    const int lane = tid & 63;
    const int wid  = tid >> 6;
    const int wm   = wid >> 1;
    const int wn   = wid & 1;
    const int quad = lane >> 4;
    const int l16  = lane & 15;
    const int key  = l16 & 7;

    // staging: each wave covers rows [wid*32, wid*32+32), 4 instrs x 8 rows.
    // lane l -> row base + (l>>3), global granule ((l&7) ^ (l>>3)) (swizzled
    // so lane-linear LDS dest yields LDS[row][g] = global g^(row&7)).
    const int srow  = wid * 32 + (lane >> 3);
    const int scolg = ((lane & 7) ^ (lane >> 3)) * 8;
    const bf16* ag = A + (size_t)(m0 + srow) * K + scolg;
    const bf16* wg = W + (size_t)(n0 + srow) * K + scolg;
    bf16* al = As + wid * 2048;
    bf16* bl = Bs + wid * 2048;

    f32x4 acc[4][4];
#pragma unroll
    for (int i = 0; i < 4; i++)
#pragma unroll
        for (int j = 0; j < 4; j++) acc[i][j] = f32x4{0.f, 0.f, 0.f, 0.f};

    for (int kt = 0; kt < K; kt += 64) {
        __syncthreads();
#pragma unroll
        for (int i = 0; i < 4; i++) {
            gload_lds16(ag + (size_t)(i * 8) * K, al + i * 8 * 64);
            gload_lds16(wg + (size_t)(i * 8) * K, bl + i * 8 * 64);
        }
        ag += 64; wg += 64;
        __syncthreads();

#pragma unroll
        for (int ks = 0; ks < 2; ks++) {
            bf16x8 af[4], bfv[4];
#pragma unroll
            for (int i = 0; i < 4; i++)
                af[i]  = *(const bf16x8*)(As + (wm * 64 + i * 16 + l16) * 64 + (((ks * 4 + quad) ^ key) * 8));
#pragma unroll
            for (int i = 0; i < 4; i++)
                bfv[i] = *(const bf16x8*)(Bs + (wn * 64 + i * 16 + l16) * 64 + (((ks * 4 + quad) ^ key) * 8));
#pragma unroll
            for (int mi = 0; mi < 4; mi++)
#pragma unroll
                for (int ni = 0; ni < 4; ni++)
                    acc[mi][ni] = MFMA16(af[mi], bfv[ni], acc[mi][ni]);
        }
    }

#pragma unroll
    for (int mi = 0; mi < 4; mi++) {
        const int row = m0 + wm * 64 + mi * 16 + quad * 4;
#pragma unroll
        for (int ni = 0; ni < 4; ni++) {
            const int col = n0 + wn * 64 + ni * 16 + l16;
#pragma unroll
            for (int r = 0; r < 4; r++)
                C[(size_t)(row + r) * ldc + col] = (OT)acc[mi][ni][r];
        }
    }
}

// ---------------------------------------------------------------------------
// Fused per-head RMSNorm (over 128) + RoPE, in place on q (16 heads) and
// k (4 heads) inside qkv [8192, 3072] (bf16). fc/norm weights are f32.
// Q heads additionally scaled by (1/sqrt(128))*log2(e) for exp2-domain softmax.
// ---------------------------------------------------------------------------
__global__ __launch_bounds__(256)
void normrope(bf16* __restrict__ qkv, const float* __restrict__ fc,
              const float* __restrict__ qw, const float* __restrict__ kw)
{
    const int row  = blockIdx.x * 4 + (threadIdx.x >> 6);
    const int lane = threadIdx.x & 63;
    const int slot = row % 20;
    const int tok  = row / 20;       // b*4096 + s
    const int s    = tok & 4095;

    const float* w; int off; float post;
    if (slot < 16) { off = slot * 128;               w = qw; post = 0.12751681555f; }
    else           { off = 2048 + (slot - 16) * 128; w = kw; post = 1.0f; }

    bf16* p = qkv + (size_t)tok * 3072 + off;

    bf16x2 v = *(const bf16x2*)(p + 2 * lane);
    float x0 = (float)v[0], x1 = (float)v[1];

    float ss = x0 * x0 + x1 * x1;
    ss += __shfl_xor(ss, 1);  ss += __shfl_xor(ss, 2);  ss += __shfl_xor(ss, 4);
    ss += __shfl_xor(ss, 8);  ss += __shfl_xor(ss, 16); ss += __shfl_xor(ss, 32);
    const float r = rsqrtf(ss * (1.0f / 128.0f) + 1e-6f) * post;

    const float xn0 = x0 * r * w[2 * lane], xn1 = x1 * r * w[2 * lane + 1];

    const float2 cs = ((const float2*)fc)[(size_t)s * 64 + lane];
    const float c = cs.x, sn = cs.y;

    bf16x2 o;
    o[0] = (bf16)(xn0 * c - xn1 * sn);
    o[1] = (bf16)(xn0 * sn + xn1 * c);
    *(bf16x2*)(p + 2 * lane) = o;
}

// ---------------------------------------------------------------------------
// V transpose: v[b,s,kvh,d] (strided in qkv) -> vT[b,kvh,d,s]
// LDS tile transpose: 64 s x 128 d per block; coalesced reads (256B rows)
// and coalesced writes (128B half-rows x2).
// ---------------------------------------------------------------------------
__global__ __launch_bounds__(256)
void transpose_v(const bf16* __restrict__ qkv, bf16* __restrict__ vT)
{
    __shared__ bf16 T[64][130];
    const int st = blockIdx.x;        // s-tile (64 rows)
    const int bk = blockIdx.y;        // b*4 + kvh
    const int b = bk >> 2, kvh = bk & 3;
    const int w = threadIdx.x >> 6, lane = threadIdx.x & 63;
    const int s0 = st * 64;

    const bf16* src = qkv + (size_t)(b * 4096 + s0) * 3072 + 2560 + kvh * 128;
#pragma unroll
    for (int i = 0; i < 16; i++) {
        const int s = w * 16 + i;
        const bf16x2 v = *(const bf16x2*)(src + (size_t)s * 3072 + 2 * lane);
        *(bf16x2*)(&T[s][2 * lane]) = v;
    }
    __syncthreads();

    bf16* dst = vT + ((size_t)bk * 128) * 4096 + s0;
#pragma unroll
    for (int i = 0; i < 16; i++) {
        const int d = w * 32 + 2 * i + (lane >> 5);
        const int s = (lane & 31) * 2;
        bf16x2 o;
        o[0] = T[s][d];
        o[1] = T[s + 1][d];
        *(bf16x2*)(dst + (size_t)d * 4096 + s) = o;
    }
}

// ---------------------------------------------------------------------------
// Causal flash attention, GQA 4:1. Q-tile 128 (4 waves x 32 rows), KV-tile 64.
// Block processes q-tile pair (bx, 31-bx): uniform 66 units/block, 512 blocks.
//
// R5 structure (measured best, 263 us): K double-buffered (Ks[t&1]), V
// single-buffered, staged via async global_load_lds with XOR-8 granule
// swizzle. LDS 64 KB. Two barriers per tile.
//
// T15 software pipeline (one tile of QK lookahead): at tile t the softmax
// consumes sacc produced at the END of tile t-1 (separated by PV[t-1],
// barrier, staging issue -> MFMA latency fully hidden); after the (E)
// barrier, QK[t+1] is issued FIRST (so its results are ready long before
// the next softmax) and then PV[t] (its Ps-lgkm covered by the QK issue).
// Schedule per step:
//   softmax(sacc[t]) -> Ps      [VALU; input one tile old]
//   (E) barrier                  [V[t], K[t+1] landed]
//   QK[t+1] -> other sacc        [MFMA]
//   PV[t]                        [MFMA]
//   (A) barrier; issue V[t+1], K[t+2]
// ntiles is always even -> loop unrolled 2x with named sA/sB. Defer-max
// (THR=8, exp2 domain); setprio(1) around MFMA clusters.
// ---------------------------------------------------------------------------
__global__ __launch_bounds__(256, 2)
void flash(const bf16* __restrict__ qkv, const bf16* __restrict__ vT,
           bf16* __restrict__ out)
{
    const int bh  = blockIdx.y;
    const int b   = bh >> 4, h = bh & 15;
    const int kvh = h >> 2;

    const int tid  = threadIdx.x;
    const int lane = tid & 63;
    const int wid  = tid >> 6;
    const int quad = lane >> 4;
    const int l16  = lane & 15;
    const int key  = l16 & 7;        // read-side swizzle key (row&7 == l16&7 everywhere)

    __shared__ bf16 Ks[2][64 * 128]; // [kv][d], 16 granules/row, swizzled
    __shared__ bf16 Vs[128 * 64];    // [d][kv], 8 granules/row, swizzled
    __shared__ bf16 Ps[128 * 64];    // [q][kv], 8 granules/row, swizzled, wave-private rows

    const bf16* kbase = qkv + (size_t)b * 4096 * 3072 + 2048 + kvh * 128;
    const bf16* vbase = vT + ((size_t)(b * 4 + kvh) * 128) * 4096;

    // staging lane decomposition
    const int krow_off = lane >> 4;            // 0..3   (4 rows / 1KB instr)
    const int kcolg    = lane & 15;            // 16B granule within 256B K row
    const int vrow_off = lane >> 3;            // 0..7   (8 rows / 1KB instr)
    const int vcolg    = lane & 7;             // granule within 128B V row

    for (int pass = 0; pass < 2; ++pass) {
        const int qt = pass ? (31 - blockIdx.x) : blockIdx.x;
        const int q0 = qt * 128;
        const int ntiles = qt * 2 + 2;          // always even

        __syncthreads();   // buffers free from previous pass, staging drained
        // preload K[0] -> Ks[0]
#pragma unroll
        for (int i = 0; i < 4; i++) {
            const int r0 = wid * 16 + i * 4;
            const int rk = r0 + krow_off;
            const int gc = (kcolg ^ (rk & 7)) * 8;
            gload_lds16(kbase + (size_t)rk * 3072 + gc, &Ks[0][r0 * 128]);
        }

        // Q fragments, 2 m-tiles x 4 k-steps (overlaps preload)
        bf16x8 qf[2][4];
        const bf16* qbase = qkv + ((size_t)(b * 4096 + q0 + wid * 32)) * 3072 + h * 128;
#pragma unroll
        for (int mt = 0; mt < 2; mt++)
#pragma unroll
            for (int ks = 0; ks < 4; ks++)
                qf[mt][ks] = *(const bf16x8*)(qbase + (size_t)(mt * 16 + l16) * 3072 + ks * 32 + quad * 8);

        f32x4 oacc[2][8];
#pragma unroll
        for (int mt = 0; mt < 2; mt++)
#pragma unroll
            for (int nd = 0; nd < 8; nd++) oacc[mt][nd] = f32x4{0.f, 0.f, 0.f, 0.f};
        float mrow[2], lrow[2];
#pragma unroll
        for (int mt = 0; mt < 2; mt++) { mrow[mt] = -__builtin_inff(); lrow[mt] = 0.f; }

        __syncthreads();   // K[0] landed

        // issue V[0] -> Vs and K[1] -> Ks[1] (ntiles >= 2 always)
#pragma unroll
        for (int i = 0; i < 4; i++) {
            const int r0 = wid * 32 + i * 8;
            const int dv = r0 + vrow_off;
            const int gc = (vcolg ^ (dv & 7)) * 8;
            gload_lds16(vbase + (size_t)dv * 4096 + gc, &Vs[r0 * 64]);
        }
#pragma unroll
        for (int i = 0; i < 4; i++) {
            const int r0 = wid * 16 + i * 4;
            const int rk = r0 + krow_off;
            const int gc = (kcolg ^ (rk & 7)) * 8;
            gload_lds16(kbase + (size_t)(64 + rk) * 3072 + gc, &Ks[1][r0 * 128]);
        }

        f32x4 sA[2][4], sB[2][4];

        // prologue QK[0] -> sA (from Ks[0])
        {
#pragma unroll
            for (int mt = 0; mt < 2; mt++)
#pragma unroll
                for (int nt = 0; nt < 4; nt++) sA[mt][nt] = f32x4{0.f, 0.f, 0.f, 0.f};
            __builtin_amdgcn_s_setprio(1);
#pragma unroll
            for (int ks = 0; ks < 4; ks++) {
                bf16x8 kf[4];
#pragma unroll
                for (int nt = 0; nt < 4; nt++)
                    kf[nt] = *(const bf16x8*)(&Ks[0][(nt * 16 + l16) * 128 + (((ks * 4 + quad) ^ key) * 8)]);
#pragma unroll
                for (int mt = 0; mt < 2; mt++)
#pragma unroll
                    for (int nt = 0; nt < 4; nt++)
                        sA[mt][nt] = MFMA16(kf[nt], qf[mt][ks], sA[mt][nt]);
            }
            __builtin_amdgcn_s_setprio(0);
        }

        // one pipeline step: softmax(SA of tile t); (E); QK[t+1]->SB; PV[t];
        // (A); issue V[t+1], K[t+2]
        auto step = [&](int t, f32x4 (&SA)[2][4], f32x4 (&SB)[2][4]) {
            const int kv0 = t * 64;

            if (kv0 + 63 > q0) {   // diagonal tiles: causal mask (kv > q)
#pragma unroll
                for (int mt = 0; mt < 2; mt++) {
                    const int qg = q0 + wid * 32 + mt * 16 + l16;
#pragma unroll
                    for (int nt = 0; nt < 4; nt++)
#pragma unroll
                        for (int r = 0; r < 4; r++) {
                            const int kvg = kv0 + nt * 16 + quad * 4 + r;
                            if (kvg > qg) SA[mt][nt][r] = -1e30f;
                        }
                }
            }

            // ---- online softmax: lane-local row (q = l16) ----
            float pm[2];
#pragma unroll
            for (int mt = 0; mt < 2; mt++) {
                float t8[8];
#pragma unroll
                for (int nt = 0; nt < 4; nt++) {
                    t8[2 * nt]     = fmaxf(SA[mt][nt][0], SA[mt][nt][1]);
                    t8[2 * nt + 1] = fmaxf(SA[mt][nt][2], SA[mt][nt][3]);
                }
                float m = fmaxf(fmaxf(fmaxf(t8[0], t8[1]), fmaxf(t8[2], t8[3])),
                                fmaxf(fmaxf(t8[4], t8[5]), fmaxf(t8[6], t8[7])));
                m = fmaxf(m, __shfl_xor(m, 16));
                m = fmaxf(m, __shfl_xor(m, 32));
                pm[mt] = m;
            }

            // defer-max: skip rescale while the running max holds within THR=8
            const bool rescale =
                !__all((pm[0] - mrow[0] <= 8.f) && (pm[1] - mrow[1] <= 8.f));
            if (rescale) {
#pragma unroll
                for (int mt = 0; mt < 2; mt++) {
                    const float mnew  = fmaxf(mrow[mt], pm[mt]);
                    const float alpha = exp2f(mrow[mt] - mnew);
                    mrow[mt] = mnew;
                    lrow[mt] *= alpha;
                    float ar[4];   // transpose alpha (q=l16) -> PV rows (q=quad*4+r)
#pragma unroll
                    for (int r = 0; r < 4; r++) ar[r] = __shfl(alpha, quad * 4 + r);
#pragma unroll
                    for (int nd = 0; nd < 8; nd++)
#pragma unroll
                        for (int r = 0; r < 4; r++) oacc[mt][nd][r] *= ar[r];
                }
            }

            // exps + packed P stores (4 consecutive kv -> b64, swizzled) + sums
#pragma unroll
            for (int mt = 0; mt < 2; mt++) {
                const int prow = wid * 32 + mt * 16 + l16;
                float sn[4];
#pragma unroll
                for (int nt = 0; nt < 4; nt++) {
                    const float p0 = exp2f(SA[mt][nt][0] - mrow[mt]);
                    const float p1 = exp2f(SA[mt][nt][1] - mrow[mt]);
                    const float p2 = exp2f(SA[mt][nt][2] - mrow[mt]);
                    const float p3 = exp2f(SA[mt][nt][3] - mrow[mt]);
                    sn[nt] = (p0 + p1) + (p2 + p3);
                    bf16x4 h4;
                    h4[0] = (bf16)p0; h4[1] = (bf16)p1;
                    h4[2] = (bf16)p2; h4[3] = (bf16)p3;
                    const int g = (2 * nt + (quad >> 1)) ^ key;
                    *(bf16x4*)(&Ps[prow * 64 + g * 8 + (quad & 1) * 4]) = h4;
                }
                float s = (sn[0] + sn[1]) + (sn[2] + sn[3]);
                s += __shfl_xor(s, 16);
                s += __shfl_xor(s, 32);
                lrow[mt] += s;
            }

            __syncthreads();   // (E) V[t] and K[t+1] landed

            // QK[t+1] first (results needed soonest, covers Ps->PV lgkm)
            if (t + 1 < ntiles) {
#pragma unroll
                for (int mt = 0; mt < 2; mt++)
#pragma unroll
                    for (int nt = 0; nt < 4; nt++) SB[mt][nt] = f32x4{0.f, 0.f, 0.f, 0.f};
                __builtin_amdgcn_s_setprio(1);
#pragma unroll
                for (int ks = 0; ks < 4; ks++) {
                    bf16x8 kf[4];
#pragma unroll
                    for (int nt = 0; nt < 4; nt++)
                        kf[nt] = *(const bf16x8*)(&Ks[(t + 1) & 1][(nt * 16 + l16) * 128 + (((ks * 4 + quad) ^ key) * 8)]);
#pragma unroll
                    for (int mt = 0; mt < 2; mt++)
#pragma unroll
                        for (int nt = 0; nt < 4; nt++)
                            SB[mt][nt] = MFMA16(kf[nt], qf[mt][ks], SB[mt][nt]);
                }
                __builtin_amdgcn_s_setprio(0);
            }

            // O += P V
            __builtin_amdgcn_s_setprio(1);
#pragma unroll
            for (int ks = 0; ks < 2; ks++) {
                bf16x8 pf[2];
#pragma unroll
                for (int mt = 0; mt < 2; mt++)
                    pf[mt] = *(const bf16x8*)(&Ps[(wid * 32 + mt * 16 + l16) * 64 + (((ks * 4 + quad) ^ key) * 8)]);
#pragma unroll
                for (int nd = 0; nd < 8; nd++) {
                    const bf16x8 vf = *(const bf16x8*)(&Vs[(nd * 16 + l16) * 64 + (((ks * 4 + quad) ^ key) * 8)]);
#pragma unroll
                    for (int mt = 0; mt < 2; mt++)
                        oacc[mt][nd] = MFMA16(pf[mt], vf, oacc[mt][nd]);
                }
            }
            __builtin_amdgcn_s_setprio(0);

            if (t + 1 < ntiles) {
                __syncthreads();   // (A) all waves done reading Vs / Ks[t&1]
                const int kvv = (t + 1) * 64;
#pragma unroll
                for (int i = 0; i < 4; i++) {
                    const int r0 = wid * 32 + i * 8;
                    const int dv = r0 + vrow_off;
                    const int gc = (vcolg ^ (dv & 7)) * 8;
                    gload_lds16(vbase + (size_t)dv * 4096 + kvv + gc, &Vs[r0 * 64]);
                }
                if (t + 2 < ntiles) {
                    const int kvn = (t + 2) * 64;
#pragma unroll
                    for (int i = 0; i < 4; i++) {
                        const int r0 = wid * 16 + i * 4;
                        const int rk = r0 + krow_off;
                        const int gc = (kcolg ^ (rk & 7)) * 8;
                        gload_lds16(kbase + (size_t)(kvn + rk) * 3072 + gc, &Ks[t & 1][r0 * 128]);
                    }
                }
            }
        };

        for (int t = 0; t < ntiles; t += 2) {
            step(t,     sA, sB);
            step(t + 1, sB, sA);
        }

        // epilogue: O / l -> out[b, s, h*128 + d]; 1/l transposed to PV rows
#pragma unroll
        for (int mt = 0; mt < 2; mt++) {
            const float inv = 1.0f / lrow[mt];
            float invr[4];
#pragma unroll
            for (int r = 0; r < 4; r++) invr[r] = __shfl(inv, quad * 4 + r);
#pragma unroll
            for (int r = 0; r < 4; r++) {
                const size_t srow = (size_t)(b * 4096 + q0 + wid * 32 + mt * 16 + quad * 4 + r);
#pragma unroll
                for (int nd = 0; nd < 8; nd++)
                    out[srow * 2048 + h * 128 + nd * 16 + l16] = (bf16)(oacc[mt][nd][r] * invr[r]);
            }
        }
    }
}

// ---------------------------------------------------------------------------
extern "C" void kernel_launch(void* const* d_in, const int* in_sizes, int n_in,
                              void* d_out, int out_size, void* d_ws, size_t ws_size,
                              hipStream_t stream)
{
    const float* x   = (const float*)d_in[0];
    const float* fc  = (const float*)d_in[1];
    const float* wq  = (const float*)d_in[2];
    const float* wk  = (const float*)d_in[3];
    const float* wv  = (const float*)d_in[4];
    const float* wo  = (const float*)d_in[5];
    const float* qnw = (const float*)d_in[6];
    const float* knw = (const float*)d_in[7];
    float* out = (float*)d_out;

    // workspace layout (100 MB total, with aliasing):
    //   [0,        50331648)  qkv bf16 [8192,3072]
    //   [50331648, 58720256)  vT  bf16 [2,4,128,4096]
    //   [58720256, 92274688)  xb (x as bf16) during gemm1, then att (flash out)
    //   [92274688, 104857600) wqkv bf16 [3072,2048] during gemm1, then wo bf16
    char* ws = (char*)d_ws;
    bf16* qkv = (bf16*)ws;
    bf16* vT  = (bf16*)(ws + 50331648);
    bf16* xb  = (bf16*)(ws + 58720256);
    bf16* att = xb;
    bf16* wb  = (bf16*)(ws + 92274688);
    bf16* wob = wb;

    // 0) casts: x -> bf16, [wq;wk;wv] -> bf16 (contiguous rows)
    cast_f32_bf16<<<dim3(8192), 256, 0, stream>>>(x, xb, 2097152);
    cast_f32_bf16<<<dim3(2048), 256, 0, stream>>>(wq, wb, 524288);
    cast_f32_bf16<<<dim3(512),  256, 0, stream>>>(wk, wb + 2048 * 2048, 131072);
    cast_f32_bf16<<<dim3(512),  256, 0, stream>>>(wv, wb + 2560 * 2048, 131072);
    // 1) fused QKV projection: qkv[8192,3072] = xb @ wb^T (BK=64, swizzled LDS)
    gemm_bt<bf16><<<dim3(24, 64), 256, 0, stream>>>(xb, wb, 2048, 3072, qkv);
    // 2) RMSNorm + RoPE on q,k heads in place (q pre-scaled for exp2 softmax)
    normrope<<<dim3(40960), 256, 0, stream>>>(qkv, fc, qnw, knw);
    // 3) V -> V^T (LDS tile transpose, coalesced both sides)
    transpose_v<<<dim3(64, 8), 256, 0, stream>>>(qkv, vT);
    // 4) causal flash attention: R5 structure (K-dbuf, V single, QK-lookahead)
    flash<<<dim3(16, 32), 256, 0, stream>>>(qkv, vT, att);
    // 5) wo -> bf16 (aliases wqkv region - dead after gemm1)
    cast_f32_bf16<<<dim3(2048), 256, 0, stream>>>(wo, wob, 524288);
    // 6) output projection: out = att @ wob^T (f32 out)
    gemm_bt<float><<<dim3(16, 64), 256, 0, stream>>>(att, wob, 2048, 2048, out);
}